// Round 4
// baseline (260.703 us; speedup 1.0000x reference)
//
#include <hip/hip_runtime.h>
#include <hip/hip_bf16.h>

typedef __attribute__((ext_vector_type(8))) short short8;
typedef __attribute__((ext_vector_type(4))) float floatx4;

#define D 128

__device__ __forceinline__ unsigned short f2bf(float f) {
    unsigned u = __float_as_uint(f);
    u += 0x7FFFu + ((u >> 16) & 1u);   // round-to-nearest-even
    return (unsigned short)(u >> 16);
}
__device__ __forceinline__ float bf2f(unsigned short h) {
    return __uint_as_float(((unsigned)h) << 16);
}
__device__ __forceinline__ float bflo(unsigned p) { return __uint_as_float(p << 16); }
__device__ __forceinline__ float bfhi(unsigned p) { return __uint_as_float(p & 0xFFFF0000u); }

// 4 edges per thread: int4 load + 4 independent atomic chains (latency hiding)
__global__ void count_kernel(const int* __restrict__ dst, int* __restrict__ cnt, int E) {
    int t4 = (blockIdx.x * blockDim.x + threadIdx.x) * 4;
    if (t4 + 3 < E) {
        int4 d = *reinterpret_cast<const int4*>(dst + t4);
        atomicAdd(&cnt[d.x], 1);
        atomicAdd(&cnt[d.y], 1);
        atomicAdd(&cnt[d.z], 1);
        atomicAdd(&cnt[d.w], 1);
    } else {
        for (int i = t4; i < E; i++) atomicAdd(&cnt[dst[i]], 1);
    }
}

__device__ __forceinline__ int block_excl_scan256(int v, int* lds, int tid) {
    int lane = tid & 63, wid = tid >> 6;
    int x = v;
    #pragma unroll
    for (int d = 1; d < 64; d <<= 1) {
        int y = __shfl_up(x, d, 64);
        if (lane >= d) x += y;
    }
    if (lane == 63) lds[wid] = x;
    __syncthreads();
    if (tid == 0) {
        int run = 0;
        #pragma unroll
        for (int i = 0; i < 4; i++) { int t2 = lds[i]; lds[i] = run; run += t2; }
    }
    __syncthreads();
    return lds[wid] + x - v;   // exclusive prefix within block
}

// phase 1: per-block sums of cnt
__global__ __launch_bounds__(256) void scan1_kernel(const int* __restrict__ cnt,
                                                    int* __restrict__ bsum, int N) {
    __shared__ int lds[4];
    int tid = threadIdx.x;
    int idx = blockIdx.x * 256 + tid;
    int v = (idx < N) ? cnt[idx] : 0;
    int lane = tid & 63, wid = tid >> 6;
    #pragma unroll
    for (int d = 32; d > 0; d >>= 1) v += __shfl_down(v, d, 64);
    if (lane == 0) lds[wid] = v;
    __syncthreads();
    if (tid == 0) bsum[blockIdx.x] = lds[0] + lds[1] + lds[2] + lds[3];
}

// phase 2: single block scans the (<=256) block sums into exclusive offsets
__global__ __launch_bounds__(256) void scan2_kernel(int* __restrict__ bsum, int nb) {
    __shared__ int lds[4];
    int tid = threadIdx.x;
    int v = (tid < nb) ? bsum[tid] : 0;
    int e = block_excl_scan256(v, lds, tid);
    if (tid < nb) bsum[tid] = e;
}

// phase 3: apply offsets, write row_ptr/row_next/dinv
__global__ __launch_bounds__(256) void scan3_kernel(const int* __restrict__ cnt,
                                                    const int* __restrict__ bsum,
                                                    int* __restrict__ row_ptr,
                                                    int* __restrict__ row_next,
                                                    float* __restrict__ dinv, int N, int E) {
    __shared__ int lds[4];
    int tid = threadIdx.x;
    int idx = blockIdx.x * 256 + tid;
    int v = (idx < N) ? cnt[idx] : 0;
    int e = bsum[blockIdx.x] + block_excl_scan256(v, lds, tid);
    if (idx < N) {
        row_ptr[idx]  = e;
        row_next[idx] = e;
        dinv[idx] = rsqrtf((float)(v + 1));
    }
    if (idx == 0) row_ptr[N] = E;
}

// 4 edges per thread; pack (src, dinv[src]) into one 8B scattered store.
__global__ void fill_kernel(const int* __restrict__ src, const int* __restrict__ dst,
                            const float* __restrict__ dinv,
                            int* __restrict__ row_next, int2* __restrict__ epack, int E) {
    int t4 = (blockIdx.x * blockDim.x + threadIdx.x) * 4;
    if (t4 + 3 < E) {
        int4 s = *reinterpret_cast<const int4*>(src + t4);
        int4 d = *reinterpret_cast<const int4*>(dst + t4);
        float c0 = dinv[s.x], c1 = dinv[s.y], c2 = dinv[s.z], c3 = dinv[s.w];
        int p0 = atomicAdd(&row_next[d.x], 1);
        int p1 = atomicAdd(&row_next[d.y], 1);
        int p2 = atomicAdd(&row_next[d.z], 1);
        int p3 = atomicAdd(&row_next[d.w], 1);
        epack[p0] = make_int2(s.x, __float_as_int(c0));
        epack[p1] = make_int2(s.y, __float_as_int(c1));
        epack[p2] = make_int2(s.z, __float_as_int(c2));
        epack[p3] = make_int2(s.w, __float_as_int(c3));
    } else {
        for (int i = t4; i < E; i++) {
            int s = src[i];
            int p = atomicAdd(&row_next[dst[i]], 1);
            epack[p] = make_int2(s, __float_as_int(dinv[s]));
        }
    }
}

// Pre-convert W (fp32 128x128, row-major [k][n]) into hi/lo bf16 MFMA B-fragment
// layout: out[((kb*4+quad)*128 + col)*8 + j] = W[(kb*32+quad*8+j)*128 + col]
__global__ __launch_bounds__(256) void wconv_kernel(const float* __restrict__ W,
                                                    unsigned short* __restrict__ whi,
                                                    unsigned short* __restrict__ wlo) {
    int tid = blockIdx.x * 256 + threadIdx.x;      // 0..16383
    int j    = tid & 7;
    int col  = (tid >> 3) & 127;
    int quad = (tid >> 10) & 3;
    int kb   = tid >> 12;
    float wv = W[(kb * 32 + quad * 8 + j) * D + col];
    unsigned u = __float_as_uint(wv);
    unsigned short h = (unsigned short)(u >> 16);          // truncate for hi
    whi[tid] = h;
    wlo[tid] = f2bf(wv - bf2f(h));
}

// C[M,128] (bf16) = A[M,128] (fp32) @ W[128,128] (fp32 via pre-split hi/lo bf16).
// hi*hi + hi*lo + lo*hi fp32-MFMA accumulate -> ~2^-17 rel, then bf16 output round.
// Block: 256 thr = 4 waves; block covers 64 rows; wave w covers cols [32w,32w+32).
__global__ __launch_bounds__(256) void gemm_kernel(const float* __restrict__ A,
                                                   const unsigned short* __restrict__ whi,
                                                   const unsigned short* __restrict__ wlo,
                                                   unsigned short* __restrict__ C, int M) {
    int lane = threadIdx.x & 63, wid = threadIdx.x >> 6;
    int quad = lane >> 4, l15 = lane & 15;
    int row0 = blockIdx.x * 64;
    int n0 = wid * 32;

    short8 bhi[2][4], blo[2][4];
    #pragma unroll
    for (int t = 0; t < 2; t++)
        #pragma unroll
        for (int kb = 0; kb < 4; kb++) {
            size_t base = ((size_t)((kb * 4 + quad) * 128 + (n0 + t * 16 + l15))) * 8;
            bhi[t][kb] = *reinterpret_cast<const short8*>(whi + base);
            blo[t][kb] = *reinterpret_cast<const short8*>(wlo + base);
        }

    #pragma unroll
    for (int rg = 0; rg < 4; rg++) {
        int r0 = row0 + rg * 16;
        int ar = r0 + l15; if (ar > M - 1) ar = M - 1;
        short8 ahi[4], alo[4];
        #pragma unroll
        for (int kb = 0; kb < 4; kb++) {
            const float4* ap = reinterpret_cast<const float4*>(A + (size_t)ar * D + kb * 32 + quad * 8);
            float4 v0 = ap[0], v1 = ap[1];
            float vv[8] = {v0.x, v0.y, v0.z, v0.w, v1.x, v1.y, v1.z, v1.w};
            short8 vh, vl;
            #pragma unroll
            for (int j = 0; j < 8; j++) {
                unsigned u = __float_as_uint(vv[j]);
                unsigned short h = (unsigned short)(u >> 16);
                vh[j] = (short)h;
                vl[j] = (short)f2bf(vv[j] - bf2f(h));
            }
            ahi[kb] = vh;
            alo[kb] = vl;
        }
        floatx4 acc0 = {0.f, 0.f, 0.f, 0.f};
        floatx4 acc1 = {0.f, 0.f, 0.f, 0.f};
        #pragma unroll
        for (int kb = 0; kb < 4; kb++) {
            acc0 = __builtin_amdgcn_mfma_f32_16x16x32_bf16(ahi[kb], bhi[0][kb], acc0, 0, 0, 0);
            acc1 = __builtin_amdgcn_mfma_f32_16x16x32_bf16(ahi[kb], bhi[1][kb], acc1, 0, 0, 0);
            acc0 = __builtin_amdgcn_mfma_f32_16x16x32_bf16(ahi[kb], blo[0][kb], acc0, 0, 0, 0);
            acc1 = __builtin_amdgcn_mfma_f32_16x16x32_bf16(ahi[kb], blo[1][kb], acc1, 0, 0, 0);
            acc0 = __builtin_amdgcn_mfma_f32_16x16x32_bf16(alo[kb], bhi[0][kb], acc0, 0, 0, 0);
            acc1 = __builtin_amdgcn_mfma_f32_16x16x32_bf16(alo[kb], bhi[1][kb], acc1, 0, 0, 0);
        }
        #pragma unroll
        for (int r = 0; r < 4; r++) {
            int orow = r0 + quad * 4 + r;
            if (orow < M) {
                C[(size_t)orow * D + n0 + l15]      = f2bf(acc0[r]);
                C[(size_t)orow * D + n0 + 16 + l15] = f2bf(acc1[r]);
            }
        }
    }
}

// One wave per node; lane holds features (2*lane, 2*lane+1) as packed bf16 (uint).
// out_i = dinv_i * sum_e c_e * h_src + dinv_i^2 * h_i + bias   (+ReLU), fp32 out.
__global__ __launch_bounds__(256) void agg_kernel(const unsigned short* __restrict__ H,
                                                  const float* __restrict__ dinv,
                                                  const int* __restrict__ row_ptr,
                                                  const int2* __restrict__ epack,
                                                  const float* __restrict__ bias,
                                                  float* __restrict__ out,
                                                  int N, int relu) {
    int node = (int)((blockIdx.x * (unsigned)blockDim.x + threadIdx.x) >> 6);
    int lane = threadIdx.x & 63;
    if (node >= N) return;
    const unsigned* H32 = (const unsigned*)H;
    float ax = 0.f, ay = 0.f;
    int beg = row_ptr[node], end = row_ptr[node + 1];
    int e = beg;
    for (; e + 4 <= end; e += 4) {
        int2 q0 = epack[e], q1 = epack[e + 1], q2 = epack[e + 2], q3 = epack[e + 3];
        float c0 = __int_as_float(q0.y), c1 = __int_as_float(q1.y);
        float c2 = __int_as_float(q2.y), c3 = __int_as_float(q3.y);
        unsigned p0 = H32[(size_t)q0.x * 64 + lane];
        unsigned p1 = H32[(size_t)q1.x * 64 + lane];
        unsigned p2 = H32[(size_t)q2.x * 64 + lane];
        unsigned p3 = H32[(size_t)q3.x * 64 + lane];
        ax += c0 * bflo(p0) + c1 * bflo(p1) + c2 * bflo(p2) + c3 * bflo(p3);
        ay += c0 * bfhi(p0) + c1 * bfhi(p1) + c2 * bfhi(p2) + c3 * bfhi(p3);
    }
    for (; e < end; e++) {
        int2 q0 = epack[e];
        float c0 = __int_as_float(q0.y);
        unsigned p0 = H32[(size_t)q0.x * 64 + lane];
        ax += c0 * bflo(p0);
        ay += c0 * bfhi(p0);
    }
    float di = dinv[node];
    unsigned ps = H32[(size_t)node * 64 + lane];
    float2 bb = ((const float2*)bias)[lane];
    float rx = di * ax + di * di * bflo(ps) + bb.x;
    float ry = di * ay + di * di * bfhi(ps) + bb.y;
    if (relu) { rx = fmaxf(rx, 0.f); ry = fmaxf(ry, 0.f); }
    float2 res; res.x = rx; res.y = ry;
    ((float2*)out)[(size_t)node * 64 + lane] = res;
}

extern "C" void kernel_launch(void* const* d_in, const int* in_sizes, int n_in,
                              void* d_out, int out_size, void* d_ws, size_t ws_size,
                              hipStream_t stream) {
    const float* x  = (const float*)d_in[0];
    const int*   ei = (const int*)d_in[1];
    const float* W1 = (const float*)d_in[2];
    const float* b1 = (const float*)d_in[3];
    const float* W2 = (const float*)d_in[4];
    const float* b2 = (const float*)d_in[5];

    int N = in_sizes[0] / D;       // 50000
    int E = in_sizes[1] / 2;       // 600000
    const int* src = ei;
    const int* dst = ei + E;

    char* ws = (char*)d_ws;
    int*   cnt      = (int*)(ws + 0);              // N ints
    int*   row_ptr  = (int*)(ws + 200064);         // N+1 ints
    int*   row_next = (int*)(ws + 400128);         // N+1 ints
    float* dinv     = (float*)(ws + 600192);       // N floats
    int*   bsum     = (int*)(ws + 800256);         // <=256 ints
    int2*  epack    = (int2*)(ws + 801280);        // E int2 (4.8 MB)
    unsigned short* whi = (unsigned short*)(ws + 5601280);   // 16384 bf16
    unsigned short* wlo = (unsigned short*)(ws + 5634048);   // 16384 bf16
    unsigned short* hfeat = (unsigned short*)(ws + 5666816); // N*D bf16 (12.8 MB)
    float* hmid = (float*)d_out;                   // layer-1 activations (fp32)
    float* outp = (float*)d_out;

    int nb = (N + 255) / 256;   // 196 scan blocks
    int eb4 = (E / 4 + 255) / 256;   // blocks for 4-edge-per-thread kernels

    hipMemsetAsync(cnt, 0, (size_t)N * sizeof(int), stream);
    count_kernel<<<eb4, 256, 0, stream>>>(dst, cnt, E);
    scan1_kernel<<<nb, 256, 0, stream>>>(cnt, bsum, N);
    scan2_kernel<<<1, 256, 0, stream>>>(bsum, nb);
    scan3_kernel<<<nb, 256, 0, stream>>>(cnt, bsum, row_ptr, row_next, dinv, N, E);
    fill_kernel<<<eb4, 256, 0, stream>>>(src, dst, dinv, row_next, epack, E);

    // layer 1: h1 = x @ W1 (bf16) ; agg + b1 + relu -> hmid (fp32, in d_out)
    wconv_kernel<<<64, 256, 0, stream>>>(W1, whi, wlo);
    gemm_kernel<<<(N + 63) / 64, 256, 0, stream>>>(x, whi, wlo, hfeat, N);
    agg_kernel<<<(N + 3) / 4, 256, 0, stream>>>(hfeat, dinv, row_ptr, epack, b1, hmid, N, 1);

    // layer 2: h2 = hmid @ W2 (bf16) ; agg + b2 -> d_out (fp32)
    wconv_kernel<<<64, 256, 0, stream>>>(W2, whi, wlo);
    gemm_kernel<<<(N + 63) / 64, 256, 0, stream>>>(hmid, whi, wlo, hfeat, N);
    agg_kernel<<<(N + 3) / 4, 256, 0, stream>>>(hfeat, dinv, row_ptr, epack, b2, outp, N, 0);
}

// Round 5
// 248.431 us; speedup vs baseline: 1.0494x; 1.0494x over previous
//
#include <hip/hip_runtime.h>
#include <hip/hip_bf16.h>

typedef __attribute__((ext_vector_type(8))) short short8;
typedef __attribute__((ext_vector_type(4))) float floatx4;

#define D 128

__device__ __forceinline__ unsigned short f2bf(float f) {
    unsigned u = __float_as_uint(f);
    u += 0x7FFFu + ((u >> 16) & 1u);   // round-to-nearest-even
    return (unsigned short)(u >> 16);
}
__device__ __forceinline__ float bf2f(unsigned short h) {
    return __uint_as_float(((unsigned)h) << 16);
}
__device__ __forceinline__ float bflo(unsigned p) { return __uint_as_float(p << 16); }
__device__ __forceinline__ float bfhi(unsigned p) { return __uint_as_float(p & 0xFFFF0000u); }

// 4 edges per thread: int4 load + 4 independent atomic chains (latency hiding)
__global__ void count_kernel(const int* __restrict__ dst, int* __restrict__ cnt, int E) {
    int t4 = (blockIdx.x * blockDim.x + threadIdx.x) * 4;
    if (t4 + 3 < E) {
        int4 d = *reinterpret_cast<const int4*>(dst + t4);
        atomicAdd(&cnt[d.x], 1);
        atomicAdd(&cnt[d.y], 1);
        atomicAdd(&cnt[d.z], 1);
        atomicAdd(&cnt[d.w], 1);
    } else {
        for (int i = t4; i < E; i++) atomicAdd(&cnt[dst[i]], 1);
    }
}

__device__ __forceinline__ int block_excl_scan256(int v, int* lds, int tid) {
    int lane = tid & 63, wid = tid >> 6;
    int x = v;
    #pragma unroll
    for (int d = 1; d < 64; d <<= 1) {
        int y = __shfl_up(x, d, 64);
        if (lane >= d) x += y;
    }
    if (lane == 63) lds[wid] = x;
    __syncthreads();
    if (tid == 0) {
        int run = 0;
        #pragma unroll
        for (int i = 0; i < 4; i++) { int t2 = lds[i]; lds[i] = run; run += t2; }
    }
    __syncthreads();
    return lds[wid] + x - v;   // exclusive prefix within block
}

// phase 1: per-block sums of cnt
__global__ __launch_bounds__(256) void scan1_kernel(const int* __restrict__ cnt,
                                                    int* __restrict__ bsum, int N) {
    __shared__ int lds[4];
    int tid = threadIdx.x;
    int idx = blockIdx.x * 256 + tid;
    int v = (idx < N) ? cnt[idx] : 0;
    int lane = tid & 63, wid = tid >> 6;
    #pragma unroll
    for (int d = 32; d > 0; d >>= 1) v += __shfl_down(v, d, 64);
    if (lane == 0) lds[wid] = v;
    __syncthreads();
    if (tid == 0) bsum[blockIdx.x] = lds[0] + lds[1] + lds[2] + lds[3];
}

// phase 2: single block scans the (<=256) block sums into exclusive offsets
__global__ __launch_bounds__(256) void scan2_kernel(int* __restrict__ bsum, int nb) {
    __shared__ int lds[4];
    int tid = threadIdx.x;
    int v = (tid < nb) ? bsum[tid] : 0;
    int e = block_excl_scan256(v, lds, tid);
    if (tid < nb) bsum[tid] = e;
}

// phase 3: apply offsets, write row_ptr/row_next/dinv
__global__ __launch_bounds__(256) void scan3_kernel(const int* __restrict__ cnt,
                                                    const int* __restrict__ bsum,
                                                    int* __restrict__ row_ptr,
                                                    int* __restrict__ row_next,
                                                    float* __restrict__ dinv, int N, int E) {
    __shared__ int lds[4];
    int tid = threadIdx.x;
    int idx = blockIdx.x * 256 + tid;
    int v = (idx < N) ? cnt[idx] : 0;
    int e = bsum[blockIdx.x] + block_excl_scan256(v, lds, tid);
    if (idx < N) {
        row_ptr[idx]  = e;
        row_next[idx] = e;
        dinv[idx] = rsqrtf((float)(v + 1));
    }
    if (idx == 0) row_ptr[N] = E;
}

// 4 edges per thread; pack (src, dinv[src]) into one 8B scattered store.
__global__ void fill_kernel(const int* __restrict__ src, const int* __restrict__ dst,
                            const float* __restrict__ dinv,
                            int* __restrict__ row_next, int2* __restrict__ epack, int E) {
    int t4 = (blockIdx.x * blockDim.x + threadIdx.x) * 4;
    if (t4 + 3 < E) {
        int4 s = *reinterpret_cast<const int4*>(src + t4);
        int4 d = *reinterpret_cast<const int4*>(dst + t4);
        float c0 = dinv[s.x], c1 = dinv[s.y], c2 = dinv[s.z], c3 = dinv[s.w];
        int p0 = atomicAdd(&row_next[d.x], 1);
        int p1 = atomicAdd(&row_next[d.y], 1);
        int p2 = atomicAdd(&row_next[d.z], 1);
        int p3 = atomicAdd(&row_next[d.w], 1);
        epack[p0] = make_int2(s.x, __float_as_int(c0));
        epack[p1] = make_int2(s.y, __float_as_int(c1));
        epack[p2] = make_int2(s.z, __float_as_int(c2));
        epack[p3] = make_int2(s.w, __float_as_int(c3));
    } else {
        for (int i = t4; i < E; i++) {
            int s = src[i];
            int p = atomicAdd(&row_next[dst[i]], 1);
            epack[p] = make_int2(s, __float_as_int(dinv[s]));
        }
    }
}

// Convert BOTH weight matrices (fp32 128x128 [k][n]) into hi/lo bf16 MFMA
// B-fragment layout: out[((kb*4+quad)*128 + col)*8 + j] = W[(kb*32+quad*8+j)*128+col]
__global__ __launch_bounds__(256) void wconv_kernel(const float* __restrict__ W1,
                                                    const float* __restrict__ W2,
                                                    unsigned short* __restrict__ whi1,
                                                    unsigned short* __restrict__ wlo1,
                                                    unsigned short* __restrict__ whi2,
                                                    unsigned short* __restrict__ wlo2) {
    int gid = blockIdx.x * 256 + threadIdx.x;      // 0..32767
    int which = gid >> 14;
    int tid = gid & 16383;
    const float* W = which ? W2 : W1;
    unsigned short* whi = which ? whi2 : whi1;
    unsigned short* wlo = which ? wlo2 : wlo1;
    int j    = tid & 7;
    int col  = (tid >> 3) & 127;
    int quad = (tid >> 10) & 3;
    int kb   = tid >> 12;
    float wv = W[(kb * 32 + quad * 8 + j) * D + col];
    unsigned u = __float_as_uint(wv);
    unsigned short h = (unsigned short)(u >> 16);          // truncate for hi
    whi[tid] = h;
    wlo[tid] = f2bf(wv - bf2f(h));
}

// Layer-1 GEMM: C[M,128](bf16) = A[M,128](fp32) @ W (pre-split hi/lo bf16).
// hi*hi + hi*lo + lo*hi fp32-MFMA accumulate -> ~2^-17 rel, then bf16 round.
__global__ __launch_bounds__(256) void gemm_f32a_kernel(const float* __restrict__ A,
                                                        const unsigned short* __restrict__ whi,
                                                        const unsigned short* __restrict__ wlo,
                                                        unsigned short* __restrict__ C, int M) {
    int lane = threadIdx.x & 63, wid = threadIdx.x >> 6;
    int quad = lane >> 4, l15 = lane & 15;
    int row0 = blockIdx.x * 64;
    int n0 = wid * 32;

    short8 bhi[2][4], blo[2][4];
    #pragma unroll
    for (int t = 0; t < 2; t++)
        #pragma unroll
        for (int kb = 0; kb < 4; kb++) {
            size_t base = ((size_t)((kb * 4 + quad) * 128 + (n0 + t * 16 + l15))) * 8;
            bhi[t][kb] = *reinterpret_cast<const short8*>(whi + base);
            blo[t][kb] = *reinterpret_cast<const short8*>(wlo + base);
        }

    #pragma unroll
    for (int rg = 0; rg < 4; rg++) {
        int r0 = row0 + rg * 16;
        int ar = r0 + l15; if (ar > M - 1) ar = M - 1;
        short8 ahi[4], alo[4];
        #pragma unroll
        for (int kb = 0; kb < 4; kb++) {
            const float4* ap = reinterpret_cast<const float4*>(A + (size_t)ar * D + kb * 32 + quad * 8);
            float4 v0 = ap[0], v1 = ap[1];
            float vv[8] = {v0.x, v0.y, v0.z, v0.w, v1.x, v1.y, v1.z, v1.w};
            short8 vh, vl;
            #pragma unroll
            for (int j = 0; j < 8; j++) {
                unsigned u = __float_as_uint(vv[j]);
                unsigned short h = (unsigned short)(u >> 16);
                vh[j] = (short)h;
                vl[j] = (short)f2bf(vv[j] - bf2f(h));
            }
            ahi[kb] = vh;
            alo[kb] = vl;
        }
        floatx4 acc0 = {0.f, 0.f, 0.f, 0.f};
        floatx4 acc1 = {0.f, 0.f, 0.f, 0.f};
        #pragma unroll
        for (int kb = 0; kb < 4; kb++) {
            acc0 = __builtin_amdgcn_mfma_f32_16x16x32_bf16(ahi[kb], bhi[0][kb], acc0, 0, 0, 0);
            acc1 = __builtin_amdgcn_mfma_f32_16x16x32_bf16(ahi[kb], bhi[1][kb], acc1, 0, 0, 0);
            acc0 = __builtin_amdgcn_mfma_f32_16x16x32_bf16(ahi[kb], blo[0][kb], acc0, 0, 0, 0);
            acc1 = __builtin_amdgcn_mfma_f32_16x16x32_bf16(ahi[kb], blo[1][kb], acc1, 0, 0, 0);
            acc0 = __builtin_amdgcn_mfma_f32_16x16x32_bf16(alo[kb], bhi[0][kb], acc0, 0, 0, 0);
            acc1 = __builtin_amdgcn_mfma_f32_16x16x32_bf16(alo[kb], bhi[1][kb], acc1, 0, 0, 0);
        }
        #pragma unroll
        for (int r = 0; r < 4; r++) {
            int orow = r0 + quad * 4 + r;
            if (orow < M) {
                C[(size_t)orow * D + n0 + l15]      = f2bf(acc0[r]);
                C[(size_t)orow * D + n0 + 16 + l15] = f2bf(acc1[r]);
            }
        }
    }
}

// Layer-2 GEMM: A is already bf16 -> alo == 0 exactly; 4 MFMAs/kb, direct loads.
__global__ __launch_bounds__(256) void gemm_bf16a_kernel(const unsigned short* __restrict__ A,
                                                         const unsigned short* __restrict__ whi,
                                                         const unsigned short* __restrict__ wlo,
                                                         unsigned short* __restrict__ C, int M) {
    int lane = threadIdx.x & 63, wid = threadIdx.x >> 6;
    int quad = lane >> 4, l15 = lane & 15;
    int row0 = blockIdx.x * 64;
    int n0 = wid * 32;

    short8 bhi[2][4], blo[2][4];
    #pragma unroll
    for (int t = 0; t < 2; t++)
        #pragma unroll
        for (int kb = 0; kb < 4; kb++) {
            size_t base = ((size_t)((kb * 4 + quad) * 128 + (n0 + t * 16 + l15))) * 8;
            bhi[t][kb] = *reinterpret_cast<const short8*>(whi + base);
            blo[t][kb] = *reinterpret_cast<const short8*>(wlo + base);
        }

    #pragma unroll
    for (int rg = 0; rg < 4; rg++) {
        int r0 = row0 + rg * 16;
        int ar = r0 + l15; if (ar > M - 1) ar = M - 1;
        short8 af[4];
        #pragma unroll
        for (int kb = 0; kb < 4; kb++)
            af[kb] = *reinterpret_cast<const short8*>(A + (size_t)ar * D + kb * 32 + quad * 8);
        floatx4 acc0 = {0.f, 0.f, 0.f, 0.f};
        floatx4 acc1 = {0.f, 0.f, 0.f, 0.f};
        #pragma unroll
        for (int kb = 0; kb < 4; kb++) {
            acc0 = __builtin_amdgcn_mfma_f32_16x16x32_bf16(af[kb], bhi[0][kb], acc0, 0, 0, 0);
            acc1 = __builtin_amdgcn_mfma_f32_16x16x32_bf16(af[kb], bhi[1][kb], acc1, 0, 0, 0);
            acc0 = __builtin_amdgcn_mfma_f32_16x16x32_bf16(af[kb], blo[0][kb], acc0, 0, 0, 0);
            acc1 = __builtin_amdgcn_mfma_f32_16x16x32_bf16(af[kb], blo[1][kb], acc1, 0, 0, 0);
        }
        #pragma unroll
        for (int r = 0; r < 4; r++) {
            int orow = r0 + quad * 4 + r;
            if (orow < M) {
                C[(size_t)orow * D + n0 + l15]      = f2bf(acc0[r]);
                C[(size_t)orow * D + n0 + 16 + l15] = f2bf(acc1[r]);
            }
        }
    }
}

// Shared aggregation body: returns (rx, ry) for this node/lane.
__device__ __forceinline__ float2 agg_body(const unsigned* __restrict__ H32,
                                           const float* __restrict__ dinv,
                                           const int* __restrict__ row_ptr,
                                           const int2* __restrict__ epack,
                                           const float* __restrict__ bias,
                                           int node, int lane) {
    float ax = 0.f, ay = 0.f;
    int beg = row_ptr[node], end = row_ptr[node + 1];
    int e = beg;
    for (; e + 8 <= end; e += 8) {
        int2 q[8];
        #pragma unroll
        for (int i = 0; i < 8; i++) q[i] = epack[e + i];
        unsigned p[8];
        #pragma unroll
        for (int i = 0; i < 8; i++) p[i] = H32[(size_t)q[i].x * 64 + lane];
        #pragma unroll
        for (int i = 0; i < 8; i++) {
            float c = __int_as_float(q[i].y);
            ax += c * bflo(p[i]);
            ay += c * bfhi(p[i]);
        }
    }
    for (; e + 4 <= end; e += 4) {
        int2 q0 = epack[e], q1 = epack[e + 1], q2 = epack[e + 2], q3 = epack[e + 3];
        unsigned p0 = H32[(size_t)q0.x * 64 + lane];
        unsigned p1 = H32[(size_t)q1.x * 64 + lane];
        unsigned p2 = H32[(size_t)q2.x * 64 + lane];
        unsigned p3 = H32[(size_t)q3.x * 64 + lane];
        float c0 = __int_as_float(q0.y), c1 = __int_as_float(q1.y);
        float c2 = __int_as_float(q2.y), c3 = __int_as_float(q3.y);
        ax += c0 * bflo(p0) + c1 * bflo(p1) + c2 * bflo(p2) + c3 * bflo(p3);
        ay += c0 * bfhi(p0) + c1 * bfhi(p1) + c2 * bfhi(p2) + c3 * bfhi(p3);
    }
    for (; e < end; e++) {
        int2 q0 = epack[e];
        unsigned p0 = H32[(size_t)q0.x * 64 + lane];
        float c0 = __int_as_float(q0.y);
        ax += c0 * bflo(p0);
        ay += c0 * bfhi(p0);
    }
    float di = dinv[node];
    unsigned ps = H32[(size_t)node * 64 + lane];
    float2 bb = ((const float2*)bias)[lane];
    float2 r;
    r.x = di * ax + di * di * bflo(ps) + bb.x;
    r.y = di * ay + di * di * bfhi(ps) + bb.y;
    return r;
}

// Layer-1 agg: + ReLU, bf16 packed output (halves write + next GEMM read).
__global__ __launch_bounds__(256) void agg_bf16out_kernel(const unsigned short* __restrict__ H,
                                                          const float* __restrict__ dinv,
                                                          const int* __restrict__ row_ptr,
                                                          const int2* __restrict__ epack,
                                                          const float* __restrict__ bias,
                                                          unsigned* __restrict__ out, int N) {
    int node = (int)((blockIdx.x * (unsigned)blockDim.x + threadIdx.x) >> 6);
    int lane = threadIdx.x & 63;
    if (node >= N) return;
    float2 r = agg_body((const unsigned*)H, dinv, row_ptr, epack, bias, node, lane);
    r.x = fmaxf(r.x, 0.f);
    r.y = fmaxf(r.y, 0.f);
    out[(size_t)node * 64 + lane] = (unsigned)f2bf(r.x) | ((unsigned)f2bf(r.y) << 16);
}

// Layer-2 agg: fp32 output to d_out.
__global__ __launch_bounds__(256) void agg_f32out_kernel(const unsigned short* __restrict__ H,
                                                         const float* __restrict__ dinv,
                                                         const int* __restrict__ row_ptr,
                                                         const int2* __restrict__ epack,
                                                         const float* __restrict__ bias,
                                                         float2* __restrict__ out, int N) {
    int node = (int)((blockIdx.x * (unsigned)blockDim.x + threadIdx.x) >> 6);
    int lane = threadIdx.x & 63;
    if (node >= N) return;
    float2 r = agg_body((const unsigned*)H, dinv, row_ptr, epack, bias, node, lane);
    out[(size_t)node * 64 + lane] = r;
}

extern "C" void kernel_launch(void* const* d_in, const int* in_sizes, int n_in,
                              void* d_out, int out_size, void* d_ws, size_t ws_size,
                              hipStream_t stream) {
    const float* x  = (const float*)d_in[0];
    const int*   ei = (const int*)d_in[1];
    const float* W1 = (const float*)d_in[2];
    const float* b1 = (const float*)d_in[3];
    const float* W2 = (const float*)d_in[4];
    const float* b2 = (const float*)d_in[5];

    int N = in_sizes[0] / D;       // 50000
    int E = in_sizes[1] / 2;       // 600000
    const int* src = ei;
    const int* dst = ei + E;

    char* ws = (char*)d_ws;
    int*   cnt      = (int*)(ws + 0);              // N ints
    int*   row_ptr  = (int*)(ws + 200064);         // N+1 ints
    int*   row_next = (int*)(ws + 400128);         // N+1 ints
    float* dinv     = (float*)(ws + 600192);       // N floats
    int*   bsum     = (int*)(ws + 800256);         // <=256 ints
    int2*  epack    = (int2*)(ws + 801280);        // E int2 (4.8 MB)
    unsigned short* whi1 = (unsigned short*)(ws + 5601280);  // 16384 bf16
    unsigned short* wlo1 = (unsigned short*)(ws + 5634048);
    unsigned short* whi2 = (unsigned short*)(ws + 5666816);
    unsigned short* wlo2 = (unsigned short*)(ws + 5699584);
    unsigned short* hfeat = (unsigned short*)(ws + 5732352); // N*D bf16 (12.8 MB)
    unsigned short* hmid  = (unsigned short*)(ws + 18532352); // N*D bf16 (12.8 MB)
    float2* outp = (float2*)d_out;

    int nb  = (N + 255) / 256;       // scan blocks
    int eb4 = (E / 4 + 255) / 256;   // 4-edge-per-thread blocks
    int gb  = (N + 63) / 64;         // gemm blocks
    int ab  = (N + 3) / 4;           // agg blocks (4 nodes/block)

    hipMemsetAsync(cnt, 0, (size_t)N * sizeof(int), stream);
    count_kernel<<<eb4, 256, 0, stream>>>(dst, cnt, E);
    scan1_kernel<<<nb, 256, 0, stream>>>(cnt, bsum, N);
    scan2_kernel<<<1, 256, 0, stream>>>(bsum, nb);
    scan3_kernel<<<nb, 256, 0, stream>>>(cnt, bsum, row_ptr, row_next, dinv, N, E);
    fill_kernel<<<eb4, 256, 0, stream>>>(src, dst, dinv, row_next, epack, E);
    wconv_kernel<<<128, 256, 0, stream>>>(W1, W2, whi1, wlo1, whi2, wlo2);

    // layer 1: h1 = x @ W1 (bf16) ; agg + b1 + relu -> hmid (bf16)
    gemm_f32a_kernel<<<gb, 256, 0, stream>>>(x, whi1, wlo1, hfeat, N);
    agg_bf16out_kernel<<<ab, 256, 0, stream>>>(hfeat, dinv, row_ptr, epack, b1, (unsigned*)hmid, N);

    // layer 2: h2 = hmid @ W2 (bf16) ; agg + b2 -> d_out (fp32)
    gemm_bf16a_kernel<<<gb, 256, 0, stream>>>(hmid, whi2, wlo2, hfeat, N);
    agg_f32out_kernel<<<ab, 256, 0, stream>>>(hfeat, dinv, row_ptr, epack, b2, outp, N);
}